// Round 15
// baseline (101.796 us; speedup 1.0000x reference)
//
#include <hip/hip_runtime.h>
#include <hip/hip_fp16.h>
#include <math.h>

#define N_NODES 50000
#define K_NEI   32
#define D_FEAT  128
#define LEAKY   0.01f

#define NPG  2                         // nodes per 32-lane group
#define GPB  8                         // 32-lane groups per 256-thread block
#define NPB  (NPG * GPB)               // 16 nodes per block
#define GRID (N_NODES / NPB)           // 3125 blocks exactly (50000 = 3125*16)

#define CHUNK_SHIFT 12                 // 4096 rows = 1 MB f16 per chunk
#define NCHUNKS     ((N_NODES + (1 << CHUNK_SHIFT) - 1) >> CHUNK_SHIFT)   // 13

// ---------- Phase 1: g = feat.a_nei, h = feat.a_ref, fh = f16(feat) ----------
__global__ __launch_bounds__(256) void precompute_kernel(
    const float* __restrict__ feat,
    const float* __restrict__ att,
    unsigned short* __restrict__ fh,
    float* __restrict__ g,
    float* __restrict__ h)
{
    const int lane = threadIdx.x & 31;
    const int row  = blockIdx.x * 8 + (threadIdx.x >> 5);
    if (row >= N_NODES) return;

    const float4 a_ref = *(const float4*)&att[4 * lane];
    const float4 a_nei = *(const float4*)&att[D_FEAT + 4 * lane];
    const float4 f     = *(const float4*)&feat[(size_t)row * D_FEAT + 4 * lane];

    float sr = f.x * a_ref.x + f.y * a_ref.y + f.z * a_ref.z + f.w * a_ref.w;
    float sn = f.x * a_nei.x + f.y * a_nei.y + f.z * a_nei.z + f.w * a_nei.w;
    #pragma unroll
    for (int off = 16; off >= 1; off >>= 1) {
        sr += __shfl_xor(sr, off, 32);
        sn += __shfl_xor(sn, off, 32);
    }
    if (lane == 0) { h[row] = sr; g[row] = sn; }

    const __half2 p0 = __floats2half2_rn(f.x, f.y);
    const __half2 p1 = __floats2half2_rn(f.z, f.w);
    uint2 st;
    st.x = *(const unsigned*)&p0;
    st.y = *(const unsigned*)&p1;
    *(uint2*)&fh[(size_t)row * D_FEAT + 4 * lane] = st;
}

// olo/ohi += wgt * f16x8(v)   (v_fma_mix_f32)
__device__ __forceinline__ void acc8(float4& olo, float4& ohi, float wgt, uint4 v) {
    const __half2 h0 = *(const __half2*)&v.x;
    const __half2 h1 = *(const __half2*)&v.y;
    const __half2 h2 = *(const __half2*)&v.z;
    const __half2 h3 = *(const __half2*)&v.w;
    olo.x += wgt * __half2float(h0.x);
    olo.y += wgt * __half2float(h0.y);
    olo.z += wgt * __half2float(h1.x);
    olo.w += wgt * __half2float(h1.y);
    ohi.x += wgt * __half2float(h2.x);
    ohi.y += wgt * __half2float(h2.y);
    ohi.z += wgt * __half2float(h3.x);
    ohi.w += wgt * __half2float(h3.y);
}

// slot refill: rank -> (w_slot, v_slot).  ## pasting avoids r12's capture bug.
#define FETCH(slot, rank) do { \
    const uint4 t_ = prsP[(rank)]; \
    w##slot = __uint_as_float(sel ? t_.w : t_.y); \
    v##slot = *(const uint4*)(fbase + (((sel ? t_.z : t_.x) << 8) + lbyte)); \
} while (0)

#define CONSUME(slot) acc8(olo, ohi, w##slot, v##slot)

// ---------- Phase 2: half-wave 16B gather, explicit 8-deep pipeline ----------
__global__ __launch_bounds__(256, 8) void gather_lds(
    const unsigned short* __restrict__ fh,
    const int*   __restrict__ nei,
    const float* __restrict__ g,
    const float* __restrict__ h,
    float*       __restrict__ out)
{
    // pairs4[grp][rank] = {idx0, w0, idx1, w1}
    __shared__ uint4 pairs4[GPB][K_NEI];   // 4 KB

    const int lane       = threadIdx.x & 31;
    const int grp        = threadIdx.x >> 5;       // 0..7
    const int group      = blockIdx.x * GPB + grp;
    const int half_shift = threadIdx.x & 32;       // 0 lower half-wave, 32 upper
    const int node0      = group * NPG;
    const unsigned lt    = (1u << lane) - 1u;

    // ---- setup: weights + chunk-sort rank, scatter (idx,w) into LDS ----
    #pragma unroll
    for (int j = 0; j < NPG; ++j) {
        const int node = node0 + j;                // grid covers N exactly

        const int idx = nei[node * K_NEI + lane];
        float sc = h[node] + g[idx];
        sc = (sc >= 0.f) ? sc : LEAKY * sc;
        const float p = __expf(sc);          // no-max softmax: |score| small, f32-safe
        float denom = p;
        #pragma unroll
        for (int off = 16; off >= 1; off >>= 1)
            denom += __shfl_xor(denom, off, 32);
        const float w = p / denom;

        const int cid = idx >> CHUNK_SHIFT;
        int rank = 0;
        #pragma unroll
        for (int c = 0; c < NCHUNKS; ++c) {
            const unsigned long long b = __ballot(cid == c);
            const unsigned bh = (unsigned)(b >> half_shift);
            rank += (c < cid)  ? __popc(bh)      : 0;
            rank += (c == cid) ? __popc(bh & lt) : 0;
        }
        ((uint2*)&pairs4[grp][rank])[j] = make_uint2((unsigned)idx, __float_as_uint(w));
    }
    // no __syncthreads(): each 32-lane group reads only its own LDS slice,
    // and both halves of a wave64 share one instruction stream (lgkmcnt-ordered).

    // ---- half-wave gather: lanes 0-15 -> node0, lanes 16-31 -> node1 ----
    const int hl  = lane & 15;                 // lane within half-group
    const int sel = (lane >> 4) & 1;           // 0: node0, 1: node1

    float4 olo = make_float4(0.f, 0.f, 0.f, 0.f);
    float4 ohi = make_float4(0.f, 0.f, 0.f, 0.f);

    const char* fbase = (const char*)fh;
    const unsigned lbyte = (unsigned)(hl << 4);   // 16 B per half-lane
    const uint4* prsP = &pairs4[grp][0];

    // ---- explicit 8-slot rotating pipeline ----
    uint4 v0, v1, v2, v3, v4, v5, v6, v7;
    float w0, w1, w2, w3, w4, w5, w6, w7;

    FETCH(0, 0); FETCH(1, 1); FETCH(2, 2); FETCH(3, 3);
    FETCH(4, 4); FETCH(5, 5); FETCH(6, 6); FETCH(7, 7);

    #pragma unroll 1
    for (int i = 0; i < K_NEI - 8; i += 8) {   // i = 0, 8, 16
        CONSUME(0); FETCH(0, i + 8);
        CONSUME(1); FETCH(1, i + 9);
        CONSUME(2); FETCH(2, i + 10);
        CONSUME(3); FETCH(3, i + 11);
        CONSUME(4); FETCH(4, i + 12);
        CONSUME(5); FETCH(5, i + 13);
        CONSUME(6); FETCH(6, i + 14);
        CONSUME(7); FETCH(7, i + 15);
    }
    CONSUME(0); CONSUME(1); CONSUME(2); CONSUME(3);
    CONSUME(4); CONSUME(5); CONSUME(6); CONSUME(7);

    // ---- ELU + store: lane owns 8 consecutive d of its node ----
    const int node = node0 + sel;
    float4 r0, r1;
    r0.x = (olo.x > 0.f) ? olo.x : (__expf(olo.x) - 1.f);
    r0.y = (olo.y > 0.f) ? olo.y : (__expf(olo.y) - 1.f);
    r0.z = (olo.z > 0.f) ? olo.z : (__expf(olo.z) - 1.f);
    r0.w = (olo.w > 0.f) ? olo.w : (__expf(olo.w) - 1.f);
    r1.x = (ohi.x > 0.f) ? ohi.x : (__expf(ohi.x) - 1.f);
    r1.y = (ohi.y > 0.f) ? ohi.y : (__expf(ohi.y) - 1.f);
    r1.z = (ohi.z > 0.f) ? ohi.z : (__expf(ohi.z) - 1.f);
    r1.w = (ohi.w > 0.f) ? ohi.w : (__expf(ohi.w) - 1.f);

    float* op = &out[(size_t)node * D_FEAT + hl * 8];
    *(float4*)op       = r0;
    *(float4*)(op + 4) = r1;
}

// ---------- Fallback (round-1 kernel) if workspace too small ----------
__global__ __launch_bounds__(256, 4) void feat_encoder_fallback(
    const float* __restrict__ feat,
    const int*   __restrict__ nei,
    const float* __restrict__ att,
    float*       __restrict__ out)
{
    const int lane = threadIdx.x & 31;
    const int node = blockIdx.x * 8 + (threadIdx.x >> 5);
    if (node >= N_NODES) return;

    const float4 a_ref = *(const float4*)&att[4 * lane];
    const float4 a_nei = *(const float4*)&att[D_FEAT + 4 * lane];

    const float4 f = *(const float4*)&feat[(size_t)node * D_FEAT + 4 * lane];
    float sref = f.x * a_ref.x + f.y * a_ref.y + f.z * a_ref.z + f.w * a_ref.w;
    #pragma unroll
    for (int off = 16; off >= 1; off >>= 1)
        sref += __shfl_xor(sref, off, 32);

    const int idx = nei[node * K_NEI + lane];
    float  s = 0.f;
    float4 o = {0.f, 0.f, 0.f, 0.f};
    #pragma unroll
    for (int k = 0; k < K_NEI; ++k) {
        const int nk = __shfl(idx, k, 32);
        const float4 v = *(const float4*)&feat[(size_t)nk * D_FEAT + 4 * lane];
        float partial = v.x * a_nei.x + v.y * a_nei.y + v.z * a_nei.z + v.w * a_nei.w;
        #pragma unroll
        for (int off = 16; off >= 1; off >>= 1)
            partial += __shfl_xor(partial, off, 32);
        float score = partial + sref;
        score = (score >= 0.f) ? score : LEAKY * score;
        const float p = __expf(score);
        s += p;
        o.x += p * v.x; o.y += p * v.y; o.z += p * v.z; o.w += p * v.w;
    }
    const float inv = 1.0f / s;
    float4 r;
    r.x = o.x * inv; r.y = o.y * inv; r.z = o.z * inv; r.w = o.w * inv;
    r.x = (r.x > 0.f) ? r.x : expm1f(r.x);
    r.y = (r.y > 0.f) ? r.y : expm1f(r.y);
    r.z = (r.z > 0.f) ? r.z : expm1f(r.z);
    r.w = (r.w > 0.f) ? r.w : expm1f(r.w);
    *(float4*)&out[(size_t)node * D_FEAT + 4 * lane] = r;
}

extern "C" void kernel_launch(void* const* d_in, const int* in_sizes, int n_in,
                              void* d_out, int out_size, void* d_ws, size_t ws_size,
                              hipStream_t stream) {
    const float* feat = (const float*)d_in[0];
    const int*   nei  = (const int*)d_in[1];
    const float* att  = (const float*)d_in[2];
    float*       out  = (float*)d_out;

    const size_t fh_bytes = (size_t)N_NODES * D_FEAT * sizeof(unsigned short); // 12.8 MB
    const size_t g_bytes  = (size_t)N_NODES * sizeof(float);                   // 200 KB
    const size_t need     = fh_bytes + 2 * g_bytes;

    if (ws_size >= need) {
        unsigned short* fh = (unsigned short*)d_ws;
        float* g = (float*)((char*)d_ws + fh_bytes);
        float* h = (float*)((char*)d_ws + fh_bytes + g_bytes);
        precompute_kernel<<<dim3((N_NODES + 7) / 8), 256, 0, stream>>>(feat, att, fh, g, h);
        gather_lds<<<dim3(GRID), 256, 0, stream>>>(fh, nei, g, h, out);
    } else {
        feat_encoder_fallback<<<dim3((N_NODES + 7) / 8), 256, 0, stream>>>(feat, nei, att, out);
    }
}

// Round 16
// 62.245 us; speedup vs baseline: 1.6354x; 1.6354x over previous
//
#include <hip/hip_runtime.h>
#include <hip/hip_fp16.h>
#include <math.h>

#define N_NODES 50000
#define K_NEI   32
#define D_FEAT  128
#define LEAKY   0.01f

#define NPG  4                         // nodes per 32-lane group (2 pairs)
#define GPB  8                         // 32-lane groups per 256-thread block
#define NPB  (NPG * GPB)               // 32 nodes per block
#define GRID ((N_NODES + NPB - 1) / NPB)   // 1563 blocks (~6.1/CU at 4 blocks/CU)

#define CHUNK_SHIFT 12                 // 4096 rows = 1 MB f16 per chunk
#define NCHUNKS     ((N_NODES + (1 << CHUNK_SHIFT) - 1) >> CHUNK_SHIFT)   // 13

// ---------- Phase 1: g = feat.a_nei, h = feat.a_ref, fh = f16(feat) ----------
__global__ __launch_bounds__(256) void precompute_kernel(
    const float* __restrict__ feat,
    const float* __restrict__ att,
    unsigned short* __restrict__ fh,
    float* __restrict__ g,
    float* __restrict__ h)
{
    const int lane = threadIdx.x & 31;
    const int row  = blockIdx.x * 8 + (threadIdx.x >> 5);
    if (row >= N_NODES) return;

    const float4 a_ref = *(const float4*)&att[4 * lane];
    const float4 a_nei = *(const float4*)&att[D_FEAT + 4 * lane];
    const float4 f     = *(const float4*)&feat[(size_t)row * D_FEAT + 4 * lane];

    float sr = f.x * a_ref.x + f.y * a_ref.y + f.z * a_ref.z + f.w * a_ref.w;
    float sn = f.x * a_nei.x + f.y * a_nei.y + f.z * a_nei.z + f.w * a_nei.w;
    #pragma unroll
    for (int off = 16; off >= 1; off >>= 1) {
        sr += __shfl_xor(sr, off, 32);
        sn += __shfl_xor(sn, off, 32);
    }
    if (lane == 0) { h[row] = sr; g[row] = sn; }

    const __half2 p0 = __floats2half2_rn(f.x, f.y);
    const __half2 p1 = __floats2half2_rn(f.z, f.w);
    uint2 st;
    st.x = *(const unsigned*)&p0;
    st.y = *(const unsigned*)&p1;
    *(uint2*)&fh[(size_t)row * D_FEAT + 4 * lane] = st;
}

// oLo/oHi += wgt * f16x8(v)   (v_fma_mix_f32)
__device__ __forceinline__ void acc8(float4& oLo, float4& oHi, float wgt, uint4 v) {
    const __half2 h0 = *(const __half2*)&v.x;
    const __half2 h1 = *(const __half2*)&v.y;
    const __half2 h2 = *(const __half2*)&v.z;
    const __half2 h3 = *(const __half2*)&v.w;
    oLo.x += wgt * __half2float(h0.x);
    oLo.y += wgt * __half2float(h0.y);
    oLo.z += wgt * __half2float(h1.x);
    oLo.w += wgt * __half2float(h1.y);
    oHi.x += wgt * __half2float(h2.x);
    oHi.y += wgt * __half2float(h2.y);
    oHi.z += wgt * __half2float(h3.x);
    oHi.w += wgt * __half2float(h3.y);
}

// slot refill from stream A (nodes 0,1) or B (nodes 2,3).
#define FETCHA(slot, rank) do { \
    const uint4 t_ = pA[(rank)]; \
    w##slot = __uint_as_float(sel ? t_.w : t_.y); \
    v##slot = *(const uint4*)(fbase + (((sel ? t_.z : t_.x) << 8) + lbyte)); \
} while (0)
#define FETCHB(slot, rank) do { \
    const uint4 t_ = pB[(rank)]; \
    w##slot = __uint_as_float(sel ? t_.w : t_.y); \
    v##slot = *(const uint4*)(fbase + (((sel ? t_.z : t_.x) << 8) + lbyte)); \
} while (0)
#define CONSA(slot) acc8(aLo, aHi, w##slot, v##slot)
#define CONSB(slot) acc8(bLo, bHi, w##slot, v##slot)

// ---------- Phase 2: half-wave 16B gather, 8-deep pipeline, 128-VGPR budget --
__global__ __launch_bounds__(256, 4) void gather_lds(
    const unsigned short* __restrict__ fh,
    const int*   __restrict__ nei,
    const float* __restrict__ g,
    const float* __restrict__ h,
    float*       __restrict__ out)
{
    // pairsA[grp][rank] = {idx0,w0,idx1,w1} (nodes 0,1); pairsB = nodes 2,3
    __shared__ uint4 pairsA[GPB][K_NEI];   // 4 KB
    __shared__ uint4 pairsB[GPB][K_NEI];   // 4 KB

    const int lane       = threadIdx.x & 31;
    const int grp        = threadIdx.x >> 5;       // 0..7
    const int group      = blockIdx.x * GPB + grp;
    const int half_shift = threadIdx.x & 32;       // 0 lower half-wave, 32 upper
    const int node0      = group * NPG;
    const unsigned lt    = (1u << lane) - 1u;

    // ---- setup: weights + chunk-sort rank, scatter (idx,w) into LDS ----
    #pragma unroll
    for (int j = 0; j < NPG; ++j) {
        const int  node  = node0 + j;
        const bool valid = (node < N_NODES);

        const int idx = valid ? nei[node * K_NEI + lane] : 0;
        float sc = valid ? (h[node] + g[idx]) : 0.f;
        sc = (sc >= 0.f) ? sc : LEAKY * sc;
        const float p = __expf(sc);          // no-max softmax: |score| small, f32-safe
        float denom = p;
        #pragma unroll
        for (int off = 16; off >= 1; off >>= 1)
            denom += __shfl_xor(denom, off, 32);
        const float w = valid ? (p / denom) : 0.f;   // phantom node: weight 0

        const int cid = idx >> CHUNK_SHIFT;
        int rank = 0;
        #pragma unroll
        for (int c = 0; c < NCHUNKS; ++c) {
            const unsigned long long b = __ballot(cid == c);
            const unsigned bh = (unsigned)(b >> half_shift);
            rank += (c < cid)  ? __popc(bh)      : 0;
            rank += (c == cid) ? __popc(bh & lt) : 0;
        }
        if (j < 2) ((uint2*)&pairsA[grp][rank])[j]     = make_uint2((unsigned)idx, __float_as_uint(w));
        else       ((uint2*)&pairsB[grp][rank])[j - 2] = make_uint2((unsigned)idx, __float_as_uint(w));
    }
    // no __syncthreads(): each 32-lane group reads only its own LDS slice,
    // and both halves of a wave64 share one instruction stream (lgkmcnt-ordered).

    // ---- half-wave gather: lanes 0-15 -> even node, 16-31 -> odd node ----
    const int hl  = lane & 15;
    const int sel = (lane >> 4) & 1;

    float4 aLo = make_float4(0.f, 0.f, 0.f, 0.f);
    float4 aHi = make_float4(0.f, 0.f, 0.f, 0.f);
    float4 bLo = make_float4(0.f, 0.f, 0.f, 0.f);
    float4 bHi = make_float4(0.f, 0.f, 0.f, 0.f);

    const char* fbase = (const char*)fh;
    const unsigned lbyte = (unsigned)(hl << 4);   // 16 B per half-lane
    const uint4* pA = &pairsA[grp][0];
    const uint4* pB = &pairsB[grp][0];

    // ---- 8-slot rotating pipeline over 64 items (A0,B0,A1,B1,...) ----
    uint4 v0, v1, v2, v3, v4, v5, v6, v7;
    float w0, w1, w2, w3, w4, w5, w6, w7;

    FETCHA(0, 0); FETCHB(1, 0); FETCHA(2, 1); FETCHB(3, 1);
    FETCHA(4, 2); FETCHB(5, 2); FETCHA(6, 3); FETCHB(7, 3);

    #pragma unroll 1
    for (int i = 0; i < 2 * K_NEI - 8; i += 8) {   // i = 0,8,...,48
        CONSA(0); FETCHA(0, (i + 8)  >> 1);
        CONSB(1); FETCHB(1, (i + 8)  >> 1);
        CONSA(2); FETCHA(2, (i + 10) >> 1);
        CONSB(3); FETCHB(3, (i + 10) >> 1);
        CONSA(4); FETCHA(4, (i + 12) >> 1);
        CONSB(5); FETCHB(5, (i + 12) >> 1);
        CONSA(6); FETCHA(6, (i + 14) >> 1);
        CONSB(7); FETCHB(7, (i + 14) >> 1);
    }
    CONSA(0); CONSB(1); CONSA(2); CONSB(3);
    CONSA(4); CONSB(5); CONSA(6); CONSB(7);

    // ---- ELU + guarded store: lane owns 8 consecutive d of its nodes ----
    const int nodeA = node0 + sel;
    const int nodeB = node0 + 2 + sel;
    float4 r0, r1;

    r0.x = (aLo.x > 0.f) ? aLo.x : (__expf(aLo.x) - 1.f);
    r0.y = (aLo.y > 0.f) ? aLo.y : (__expf(aLo.y) - 1.f);
    r0.z = (aLo.z > 0.f) ? aLo.z : (__expf(aLo.z) - 1.f);
    r0.w = (aLo.w > 0.f) ? aLo.w : (__expf(aLo.w) - 1.f);
    r1.x = (aHi.x > 0.f) ? aHi.x : (__expf(aHi.x) - 1.f);
    r1.y = (aHi.y > 0.f) ? aHi.y : (__expf(aHi.y) - 1.f);
    r1.z = (aHi.z > 0.f) ? aHi.z : (__expf(aHi.z) - 1.f);
    r1.w = (aHi.w > 0.f) ? aHi.w : (__expf(aHi.w) - 1.f);
    if (nodeA < N_NODES) {
        float* op = &out[(size_t)nodeA * D_FEAT + hl * 8];
        *(float4*)op       = r0;
        *(float4*)(op + 4) = r1;
    }

    r0.x = (bLo.x > 0.f) ? bLo.x : (__expf(bLo.x) - 1.f);
    r0.y = (bLo.y > 0.f) ? bLo.y : (__expf(bLo.y) - 1.f);
    r0.z = (bLo.z > 0.f) ? bLo.z : (__expf(bLo.z) - 1.f);
    r0.w = (bLo.w > 0.f) ? bLo.w : (__expf(bLo.w) - 1.f);
    r1.x = (bHi.x > 0.f) ? bHi.x : (__expf(bHi.x) - 1.f);
    r1.y = (bHi.y > 0.f) ? bHi.y : (__expf(bHi.y) - 1.f);
    r1.z = (bHi.z > 0.f) ? bHi.z : (__expf(bHi.z) - 1.f);
    r1.w = (bHi.w > 0.f) ? bHi.w : (__expf(bHi.w) - 1.f);
    if (nodeB < N_NODES) {
        float* op = &out[(size_t)nodeB * D_FEAT + hl * 8];
        *(float4*)op       = r0;
        *(float4*)(op + 4) = r1;
    }
}

// ---------- Fallback (round-1 kernel) if workspace too small ----------
__global__ __launch_bounds__(256, 4) void feat_encoder_fallback(
    const float* __restrict__ feat,
    const int*   __restrict__ nei,
    const float* __restrict__ att,
    float*       __restrict__ out)
{
    const int lane = threadIdx.x & 31;
    const int node = blockIdx.x * 8 + (threadIdx.x >> 5);
    if (node >= N_NODES) return;

    const float4 a_ref = *(const float4*)&att[4 * lane];
    const float4 a_nei = *(const float4*)&att[D_FEAT + 4 * lane];

    const float4 f = *(const float4*)&feat[(size_t)node * D_FEAT + 4 * lane];
    float sref = f.x * a_ref.x + f.y * a_ref.y + f.z * a_ref.z + f.w * a_ref.w;
    #pragma unroll
    for (int off = 16; off >= 1; off >>= 1)
        sref += __shfl_xor(sref, off, 32);

    const int idx = nei[node * K_NEI + lane];
    float  s = 0.f;
    float4 o = {0.f, 0.f, 0.f, 0.f};
    #pragma unroll
    for (int k = 0; k < K_NEI; ++k) {
        const int nk = __shfl(idx, k, 32);
        const float4 v = *(const float4*)&feat[(size_t)nk * D_FEAT + 4 * lane];
        float partial = v.x * a_nei.x + v.y * a_nei.y + v.z * a_nei.z + v.w * a_nei.w;
        #pragma unroll
        for (int off = 16; off >= 1; off >>= 1)
            partial += __shfl_xor(partial, off, 32);
        float score = partial + sref;
        score = (score >= 0.f) ? score : LEAKY * score;
        const float p = __expf(score);
        s += p;
        o.x += p * v.x; o.y += p * v.y; o.z += p * v.z; o.w += p * v.w;
    }
    const float inv = 1.0f / s;
    float4 r;
    r.x = o.x * inv; r.y = o.y * inv; r.z = o.z * inv; r.w = o.w * inv;
    r.x = (r.x > 0.f) ? r.x : expm1f(r.x);
    r.y = (r.y > 0.f) ? r.y : expm1f(r.y);
    r.z = (r.z > 0.f) ? r.z : expm1f(r.z);
    r.w = (r.w > 0.f) ? r.w : expm1f(r.w);
    *(float4*)&out[(size_t)node * D_FEAT + 4 * lane] = r;
}

extern "C" void kernel_launch(void* const* d_in, const int* in_sizes, int n_in,
                              void* d_out, int out_size, void* d_ws, size_t ws_size,
                              hipStream_t stream) {
    const float* feat = (const float*)d_in[0];
    const int*   nei  = (const int*)d_in[1];
    const float* att  = (const float*)d_in[2];
    float*       out  = (float*)d_out;

    const size_t fh_bytes = (size_t)N_NODES * D_FEAT * sizeof(unsigned short); // 12.8 MB
    const size_t g_bytes  = (size_t)N_NODES * sizeof(float);                   // 200 KB
    const size_t need     = fh_bytes + 2 * g_bytes;

    if (ws_size >= need) {
        unsigned short* fh = (unsigned short*)d_ws;
        float* g = (float*)((char*)d_ws + fh_bytes);
        float* h = (float*)((char*)d_ws + fh_bytes + g_bytes);
        precompute_kernel<<<dim3((N_NODES + 7) / 8), 256, 0, stream>>>(feat, att, fh, g, h);
        gather_lds<<<dim3(GRID), 256, 0, stream>>>(fh, nei, g, h, out);
    } else {
        feat_encoder_fallback<<<dim3((N_NODES + 7) / 8), 256, 0, stream>>>(feat, nei, att, out);
    }
}

// Round 17
// 60.261 us; speedup vs baseline: 1.6893x; 1.0329x over previous
//
#include <hip/hip_runtime.h>
#include <hip/hip_fp16.h>
#include <math.h>

#define N_NODES 50000
#define K_NEI   32
#define D_FEAT  128
#define LEAKY   0.01f

#define NPG  2                         // nodes per 32-lane group
#define GPB  8                         // 32-lane groups per 256-thread block
#define NPB  (NPG * GPB)               // 16 nodes per block
#define GRID (N_NODES / NPB)           // 3125 blocks exactly (50000 = 3125*16)

#define CHUNK_SHIFT 12                 // 4096 rows = 1 MB f16 per chunk
#define NCHUNKS     ((N_NODES + (1 << CHUNK_SHIFT) - 1) >> CHUNK_SHIFT)   // 13

// ---------- Phase 1: g = feat.a_nei, h = feat.a_ref, fh = f16(feat) ----------
__global__ __launch_bounds__(256) void precompute_kernel(
    const float* __restrict__ feat,
    const float* __restrict__ att,
    unsigned short* __restrict__ fh,
    float* __restrict__ g,
    float* __restrict__ h)
{
    const int lane = threadIdx.x & 31;
    const int row  = blockIdx.x * 8 + (threadIdx.x >> 5);
    if (row >= N_NODES) return;

    const float4 a_ref = *(const float4*)&att[4 * lane];
    const float4 a_nei = *(const float4*)&att[D_FEAT + 4 * lane];
    const float4 f     = *(const float4*)&feat[(size_t)row * D_FEAT + 4 * lane];

    float sr = f.x * a_ref.x + f.y * a_ref.y + f.z * a_ref.z + f.w * a_ref.w;
    float sn = f.x * a_nei.x + f.y * a_nei.y + f.z * a_nei.z + f.w * a_nei.w;
    #pragma unroll
    for (int off = 16; off >= 1; off >>= 1) {
        sr += __shfl_xor(sr, off, 32);
        sn += __shfl_xor(sn, off, 32);
    }
    if (lane == 0) { h[row] = sr; g[row] = sn; }

    const __half2 p0 = __floats2half2_rn(f.x, f.y);
    const __half2 p1 = __floats2half2_rn(f.z, f.w);
    uint2 st;
    st.x = *(const unsigned*)&p0;
    st.y = *(const unsigned*)&p1;
    *(uint2*)&fh[(size_t)row * D_FEAT + 4 * lane] = st;
}

// olo/ohi += wgt * f16x8(v)   (v_fma_mix_f32)
__device__ __forceinline__ void acc8(float4& olo, float4& ohi, float wgt, uint4 v) {
    const __half2 h0 = *(const __half2*)&v.x;
    const __half2 h1 = *(const __half2*)&v.y;
    const __half2 h2 = *(const __half2*)&v.z;
    const __half2 h3 = *(const __half2*)&v.w;
    olo.x += wgt * __half2float(h0.x);
    olo.y += wgt * __half2float(h0.y);
    olo.z += wgt * __half2float(h1.x);
    olo.w += wgt * __half2float(h1.y);
    ohi.x += wgt * __half2float(h2.x);
    ohi.y += wgt * __half2float(h2.y);
    ohi.z += wgt * __half2float(h3.x);
    ohi.w += wgt * __half2float(h3.y);
}

// slot refill: rank -> (w_slot, v_slot)
#define FETCH(slot, rank) do { \
    const uint4 t_ = prsP[(rank)]; \
    w##slot = __uint_as_float(sel ? t_.w : t_.y); \
    v##slot = *(const uint4*)(fbase + (((sel ? t_.z : t_.x) << 8) + lbyte)); \
} while (0)

#define CONSUME(slot) acc8(olo, ohi, w##slot, v##slot)

// ---------- Phase 2: half-wave 16B gather, 4-deep pipeline, 64-VGPR cap ------
__global__ __launch_bounds__(256, 8) void gather_lds(
    const unsigned short* __restrict__ fh,
    const int*   __restrict__ nei,
    const float* __restrict__ g,
    const float* __restrict__ h,
    float*       __restrict__ out)
{
    // pairs4[grp][rank] = {idx0, w0, idx1, w1}
    __shared__ uint4 pairs4[GPB][K_NEI];   // 4 KB

    const int lane       = threadIdx.x & 31;
    const int grp        = threadIdx.x >> 5;       // 0..7
    const int group      = blockIdx.x * GPB + grp;
    const int half_shift = threadIdx.x & 32;       // 0 lower half-wave, 32 upper
    const int node0      = group * NPG;
    const unsigned lt    = (1u << lane) - 1u;

    // ---- setup: weights + chunk-sort rank, scatter (idx,w) into LDS ----
    #pragma unroll
    for (int j = 0; j < NPG; ++j) {
        const int node = node0 + j;                // grid covers N exactly

        const int idx = nei[node * K_NEI + lane];
        float sc = h[node] + g[idx];
        sc = (sc >= 0.f) ? sc : LEAKY * sc;
        const float p = __expf(sc);          // no-max softmax: |score| small, f32-safe
        float denom = p;
        #pragma unroll
        for (int off = 16; off >= 1; off >>= 1)
            denom += __shfl_xor(denom, off, 32);
        const float w = p / denom;

        const int cid = idx >> CHUNK_SHIFT;
        int rank = 0;
        #pragma unroll
        for (int c = 0; c < NCHUNKS; ++c) {
            const unsigned long long b = __ballot(cid == c);
            const unsigned bh = (unsigned)(b >> half_shift);
            rank += (c < cid)  ? __popc(bh)      : 0;
            rank += (c == cid) ? __popc(bh & lt) : 0;
        }
        ((uint2*)&pairs4[grp][rank])[j] = make_uint2((unsigned)idx, __float_as_uint(w));
    }
    // no __syncthreads(): each 32-lane group reads only its own LDS slice,
    // and both halves of a wave64 share one instruction stream (lgkmcnt-ordered).

    // ---- half-wave gather: lanes 0-15 -> node0, lanes 16-31 -> node1 ----
    const int hl  = lane & 15;                 // lane within half-group
    const int sel = (lane >> 4) & 1;           // 0: node0, 1: node1

    float4 olo = make_float4(0.f, 0.f, 0.f, 0.f);
    float4 ohi = make_float4(0.f, 0.f, 0.f, 0.f);

    const char* fbase = (const char*)fh;
    const unsigned lbyte = (unsigned)(hl << 4);   // 16 B per half-lane
    const uint4* prsP = &pairs4[grp][0];

    // ---- explicit 4-slot rotating pipeline (live set < 64-VGPR cap) ----
    uint4 v0, v1, v2, v3;
    float w0, w1, w2, w3;

    FETCH(0, 0); FETCH(1, 1); FETCH(2, 2); FETCH(3, 3);

    #pragma unroll 1
    for (int i = 0; i < K_NEI - 4; i += 4) {   // i = 0,4,...,24
        CONSUME(0); FETCH(0, i + 4);
        CONSUME(1); FETCH(1, i + 5);
        CONSUME(2); FETCH(2, i + 6);
        CONSUME(3); FETCH(3, i + 7);
    }
    CONSUME(0); CONSUME(1); CONSUME(2); CONSUME(3);

    // ---- ELU + store: lane owns 8 consecutive d of its node ----
    const int node = node0 + sel;
    float4 r0, r1;
    r0.x = (olo.x > 0.f) ? olo.x : (__expf(olo.x) - 1.f);
    r0.y = (olo.y > 0.f) ? olo.y : (__expf(olo.y) - 1.f);
    r0.z = (olo.z > 0.f) ? olo.z : (__expf(olo.z) - 1.f);
    r0.w = (olo.w > 0.f) ? olo.w : (__expf(olo.w) - 1.f);
    r1.x = (ohi.x > 0.f) ? ohi.x : (__expf(ohi.x) - 1.f);
    r1.y = (ohi.y > 0.f) ? ohi.y : (__expf(ohi.y) - 1.f);
    r1.z = (ohi.z > 0.f) ? ohi.z : (__expf(ohi.z) - 1.f);
    r1.w = (ohi.w > 0.f) ? ohi.w : (__expf(ohi.w) - 1.f);

    float* op = &out[(size_t)node * D_FEAT + hl * 8];
    *(float4*)op       = r0;
    *(float4*)(op + 4) = r1;
}

// ---------- Fallback (round-1 kernel) if workspace too small ----------
__global__ __launch_bounds__(256, 4) void feat_encoder_fallback(
    const float* __restrict__ feat,
    const int*   __restrict__ nei,
    const float* __restrict__ att,
    float*       __restrict__ out)
{
    const int lane = threadIdx.x & 31;
    const int node = blockIdx.x * 8 + (threadIdx.x >> 5);
    if (node >= N_NODES) return;

    const float4 a_ref = *(const float4*)&att[4 * lane];
    const float4 a_nei = *(const float4*)&att[D_FEAT + 4 * lane];

    const float4 f = *(const float4*)&feat[(size_t)node * D_FEAT + 4 * lane];
    float sref = f.x * a_ref.x + f.y * a_ref.y + f.z * a_ref.z + f.w * a_ref.w;
    #pragma unroll
    for (int off = 16; off >= 1; off >>= 1)
        sref += __shfl_xor(sref, off, 32);

    const int idx = nei[node * K_NEI + lane];
    float  s = 0.f;
    float4 o = {0.f, 0.f, 0.f, 0.f};
    #pragma unroll
    for (int k = 0; k < K_NEI; ++k) {
        const int nk = __shfl(idx, k, 32);
        const float4 v = *(const float4*)&feat[(size_t)nk * D_FEAT + 4 * lane];
        float partial = v.x * a_nei.x + v.y * a_nei.y + v.z * a_nei.z + v.w * a_nei.w;
        #pragma unroll
        for (int off = 16; off >= 1; off >>= 1)
            partial += __shfl_xor(partial, off, 32);
        float score = partial + sref;
        score = (score >= 0.f) ? score : LEAKY * score;
        const float p = __expf(score);
        s += p;
        o.x += p * v.x; o.y += p * v.y; o.z += p * v.z; o.w += p * v.w;
    }
    const float inv = 1.0f / s;
    float4 r;
    r.x = o.x * inv; r.y = o.y * inv; r.z = o.z * inv; r.w = o.w * inv;
    r.x = (r.x > 0.f) ? r.x : expm1f(r.x);
    r.y = (r.y > 0.f) ? r.y : expm1f(r.y);
    r.z = (r.z > 0.f) ? r.z : expm1f(r.z);
    r.w = (r.w > 0.f) ? r.w : expm1f(r.w);
    *(float4*)&out[(size_t)node * D_FEAT + 4 * lane] = r;
}

extern "C" void kernel_launch(void* const* d_in, const int* in_sizes, int n_in,
                              void* d_out, int out_size, void* d_ws, size_t ws_size,
                              hipStream_t stream) {
    const float* feat = (const float*)d_in[0];
    const int*   nei  = (const int*)d_in[1];
    const float* att  = (const float*)d_in[2];
    float*       out  = (float*)d_out;

    const size_t fh_bytes = (size_t)N_NODES * D_FEAT * sizeof(unsigned short); // 12.8 MB
    const size_t g_bytes  = (size_t)N_NODES * sizeof(float);                   // 200 KB
    const size_t need     = fh_bytes + 2 * g_bytes;

    if (ws_size >= need) {
        unsigned short* fh = (unsigned short*)d_ws;
        float* g = (float*)((char*)d_ws + fh_bytes);
        float* h = (float*)((char*)d_ws + fh_bytes + g_bytes);
        precompute_kernel<<<dim3((N_NODES + 7) / 8), 256, 0, stream>>>(feat, att, fh, g, h);
        gather_lds<<<dim3(GRID), 256, 0, stream>>>(fh, nei, g, h, out);
    } else {
        feat_encoder_fallback<<<dim3((N_NODES + 7) / 8), 256, 0, stream>>>(feat, nei, att, out);
    }
}